// Round 1
// baseline (2580.508 us; speedup 1.0000x reference)
//
#include <hip/hip_runtime.h>
#include <math.h>

// EntNet forward on MI355X.
// Sizes: VOC=32000, MEM=128, NSLOTS=20, NSENT=128, MAXLEN=32, QLEN=16, ANSLEN=8, B=64
// Only the first 128 flattened tokens per batch are used (tok[:, :NSENT]).
//
// Decomposition:
//   prep_kernel : s gather + Ws = s@Ww.T + Vkey + q/a1/a2 means   (1108 blocks)
//   scan_kernel : 128 sequential steps, one workgroup per slot (20 blocks x 1024 thr)
//                 state U kept unnormalized in LDS, scale inv carried in registers
//   final_kernel: attention over slots + output softmax            (64 blocks)

// ---------------------------------------------------------------- prep
__global__ __launch_bounds__(128) void prep_kernel(
    const int* __restrict__ ids, const int* __restrict__ ques, const int* __restrict__ ans,
    const float* __restrict__ E, const float* __restrict__ Ww, const float* __restrict__ Wb,
    const float* __restrict__ Vw, const float* __restrict__ Vb, const float* __restrict__ skeys,
    float* __restrict__ sT, float* __restrict__ WsT, float* __restrict__ vkey,
    float* __restrict__ qv, float* __restrict__ a1v, float* __restrict__ a2v)
{
    const int bi  = blockIdx.x;
    const int tid = threadIdx.x;   // 128
    if (bi < 1024) {
        // block = (b, group of 8 t).  s row gather + Ws row matmul.
        const int b = bi >> 4;
        const int g = bi & 15;
        __shared__ float s_l[8][128];
        for (int tt = 0; tt < 8; ++tt) {
            const int t     = g * 8 + tt;
            const int token = ids[b * 4096 + t];      // flat (NSENT*MAXLEN)=4096, first 128
            const float v   = E[token * 128 + tid];   // E row 0 is zero in the input
            s_l[tt][tid] = v;
            sT[(t * 64 + b) * 128 + tid] = v;         // layout (t, b, m)
        }
        __syncthreads();
        float acc[8];
        const float wbn = Wb[tid];
        #pragma unroll
        for (int i = 0; i < 8; ++i) acc[i] = wbn;
        const float4* wrow = (const float4*)(Ww + tid * 128);   // thread = output n
        for (int m4 = 0; m4 < 32; ++m4) {
            const float4 w = wrow[m4];
            #pragma unroll
            for (int tt = 0; tt < 8; ++tt) {
                acc[tt] += s_l[tt][m4*4+0]*w.x + s_l[tt][m4*4+1]*w.y
                         + s_l[tt][m4*4+2]*w.z + s_l[tt][m4*4+3]*w.w;
            }
        }
        for (int tt = 0; tt < 8; ++tt)
            WsT[((g*8+tt) * 64 + b) * 128 + tid] = acc[tt];     // layout (t, b, n)
    } else if (bi < 1044) {
        // Vkey[j][n] = Vb[n] + sum_m skeys[j][m]*Vw[n][m]
        const int j = bi - 1024;
        __shared__ float k_l[128];
        k_l[tid] = skeys[j * 128 + tid];
        __syncthreads();
        float acc = Vb[tid];
        const float4* vrow = (const float4*)(Vw + tid * 128);
        for (int m4 = 0; m4 < 32; ++m4) {
            const float4 w = vrow[m4];
            acc += k_l[m4*4]*w.x + k_l[m4*4+1]*w.y + k_l[m4*4+2]*w.z + k_l[m4*4+3]*w.w;
        }
        vkey[j * 128 + tid] = acc;
    } else {
        // q / a1 / a2 means per batch row
        const int b = bi - 1044;
        float sq = 0.f, s1 = 0.f, s2 = 0.f;
        for (int i = 0; i < 16; ++i) sq += E[ques[b*16+i] * 128 + tid];
        for (int i = 0; i < 8;  ++i) s1 += E[ans[(b*8+i)*2+0] * 128 + tid];
        for (int i = 0; i < 8;  ++i) s2 += E[ans[(b*8+i)*2+1] * 128 + tid];
        qv [b*128+tid] = sq * (1.f/16.f);
        a1v[b*128+tid] = s1 * 0.125f;
        a2v[b*128+tid] = s2 * 0.125f;
    }
}

// ---------------------------------------------------------------- scan
// One block per slot j. 1024 threads: thread = (b = tid>>4, n-slice nn = (tid&15)*8).
// State: U (unnormalized mem) in LDS, stride 129 to break bank conflicts.
// Deferred scale: true mem = inv_s * U. inv_s carried redundantly in every thread's
// registers (all threads recompute it identically from the block ssq each step).
// Exactly 2 __syncthreads per step.
__global__ __launch_bounds__(1024) void scan_kernel(
    const float* __restrict__ sT, const float* __restrict__ WsT,
    const float* __restrict__ vkey, const float* __restrict__ Uw,
    const float* __restrict__ Ub, const float* __restrict__ skeys,
    float* __restrict__ h_out)
{
    extern __shared__ float sm[];
    float* UwT   = sm;            // 128*128  = 16384 floats, UwT[m][n] = Uw[n][m]
    float* Um    = sm + 16384;    // 64*129   = 8256 floats
    float* ubvk  = Um + 8256;     // 128
    float* key_l = ubvk + 128;    // 128
    float* wred  = key_l + 128;   // 16

    const int j   = blockIdx.x;
    const int tid = threadIdx.x;
    const int b   = tid >> 4;
    const int nn  = (tid & 15) * 8;

    for (int i = tid; i < 16384; i += 1024)
        UwT[(i & 127) * 128 + (i >> 7)] = Uw[i];
    for (int i = tid; i < 64*129; i += 1024) Um[i] = 0.f;
    if (tid < 128) {
        ubvk[tid]  = Ub[tid] + vkey[j*128 + tid];
        key_l[tid] = skeys[j*128 + tid];
    }
    __syncthreads();

    float  inv_s = 1.f;           // scale of current U (U=0 so any finite value ok)
    float* Urow  = Um + b * 129;

    for (int t = 0; t < 128; ++t) {
        // ---- gate: g[b] = sigmoid(inv*dot(s_t[b],U[b]) + dot(s_t[b],key)) ----
        const float4* s4 = (const float4*)(sT + (t*64 + b)*128 + nn);
        const float4 sa = s4[0], sb = s4[1];
        float d1, d2;
        {
            const float* u = Urow + nn;
            const float* k = key_l + nn;
            d1 = sa.x*u[0]+sa.y*u[1]+sa.z*u[2]+sa.w*u[3]
               + sb.x*u[4]+sb.y*u[5]+sb.z*u[6]+sb.w*u[7];
            d2 = sa.x*k[0]+sa.y*k[1]+sa.z*k[2]+sa.w*k[3]
               + sb.x*k[4]+sb.y*k[5]+sb.z*k[6]+sb.w*k[7];
        }
        #pragma unroll
        for (int mask = 1; mask <= 8; mask <<= 1) {   // reduce over 16-lane b-group
            d1 += __shfl_xor(d1, mask, 64);
            d2 += __shfl_xor(d2, mask, 64);
        }
        const float gb = 1.f / (1.f + expf(-(inv_s*d1 + d2)));

        // ---- matmul: acc[i] = sum_m U[b][m] * Uw[nn+i][m] ----
        float acc[8] = {0.f,0.f,0.f,0.f,0.f,0.f,0.f,0.f};
        for (int m8 = 0; m8 < 16; ++m8) {
            #pragma unroll
            for (int k = 0; k < 8; ++k) {
                const int m = m8*8 + k;
                const float um = Urow[m];
                const float4* w4 = (const float4*)(UwT + m*128 + nn);
                const float4 wa = w4[0], wb = w4[1];
                acc[0] += um*wa.x; acc[1] += um*wa.y; acc[2] += um*wa.z; acc[3] += um*wa.w;
                acc[4] += um*wb.x; acc[5] += um*wb.y; acc[6] += um*wb.z; acc[7] += um*wb.w;
            }
        }
        __syncthreads();   // B1: all reads of old U complete

        // ---- update own slice ----
        const float4* wsp = (const float4*)(WsT + (t*64 + b)*128 + nn);
        const float4 wsa = wsp[0], wsb = wsp[1];
        const float wsv[8] = {wsa.x,wsa.y,wsa.z,wsa.w,wsb.x,wsb.y,wsb.z,wsb.w};
        float  ssq = 0.f;
        float* un  = Urow + nn;
        #pragma unroll
        for (int i = 0; i < 8; ++i) {
            float hr = inv_s*acc[i] + ubvk[nn+i] + wsv[i];
            hr = fmaxf(hr, 0.f);                       // h_cand
            const float x = inv_s*un[i] + gb*hr;       // new (unnormalized) U
            un[i] = x;
            ssq += x*x;
        }
        #pragma unroll
        for (int mask = 1; mask < 64; mask <<= 1) ssq += __shfl_xor(ssq, mask, 64);
        if ((tid & 63) == 0) wred[tid >> 6] = ssq;
        __syncthreads();   // B2: U writes + wave partials visible
        float tot = 0.f;
        #pragma unroll
        for (int w = 0; w < 16; ++w) tot += wred[w];
        inv_s = 1.f / sqrtf(tot);
        // wred is re-written only after next step's B1 -> no extra barrier needed
    }

    // h = inv * U  (normalized final memory), layout (b, j, m)
    #pragma unroll
    for (int i = 0; i < 8; ++i)
        h_out[(b*20 + j)*128 + nn + i] = inv_s * Urow[nn + i];
}

// ---------------------------------------------------------------- final
__global__ __launch_bounds__(128) void final_kernel(
    const float* __restrict__ h, const float* __restrict__ qv,
    const float* __restrict__ a1v, const float* __restrict__ a2v,
    const float* __restrict__ Hw, const float* __restrict__ Hb,
    float* __restrict__ out)
{
    const int b   = blockIdx.x;
    const int tid = threadIdx.x;    // 128
    __shared__ float hb[20][128];
    __shared__ float ql[128];
    __shared__ float ul[128];
    __shared__ float pl[20];
    __shared__ float lgt[20];
    __shared__ float red1[2], red2[2];

    for (int jj = 0; jj < 20; ++jj) hb[jj][tid] = h[(b*20+jj)*128 + tid];
    ql[tid] = qv[b*128 + tid];
    __syncthreads();
    if (tid < 20) {
        float d = 0.f;
        for (int m = 0; m < 128; ++m) d += hb[tid][m] * ql[m];
        lgt[tid] = d;
    }
    __syncthreads();
    if (tid == 0) {
        float mx = lgt[0];
        for (int jj = 1; jj < 20; ++jj) mx = fmaxf(mx, lgt[jj]);
        float s = 0.f;
        for (int jj = 0; jj < 20; ++jj) { const float e = expf(lgt[jj]-mx); pl[jj] = e; s += e; }
        const float is = 1.f / s;
        for (int jj = 0; jj < 20; ++jj) pl[jj] *= is;
    }
    __syncthreads();
    float u = 0.f;
    for (int jj = 0; jj < 20; ++jj) u += pl[jj] * hb[jj][tid];
    ul[tid] = u;
    __syncthreads();
    float acc = ql[tid] + Hb[tid];
    const float4* hwr = (const float4*)(Hw + tid*128);
    for (int m4 = 0; m4 < 32; ++m4) {
        const float4 w = hwr[m4];
        acc += ul[m4*4]*w.x + ul[m4*4+1]*w.y + ul[m4*4+2]*w.z + ul[m4*4+3]*w.w;
    }
    const float r  = fmaxf(acc, 0.f);
    float y1 = r * a1v[b*128+tid];
    float y2 = r * a2v[b*128+tid];
    #pragma unroll
    for (int mask = 1; mask < 64; mask <<= 1) {
        y1 += __shfl_xor(y1, mask, 64);
        y2 += __shfl_xor(y2, mask, 64);
    }
    if ((tid & 63) == 0) { red1[tid>>6] = y1; red2[tid>>6] = y2; }
    __syncthreads();
    if (tid == 0) {
        const float z1 = red1[0] + red1[1];
        const float z2 = red2[0] + red2[1];
        const float mx = fmaxf(z1, z2);
        const float e1 = expf(z1-mx), e2 = expf(z2-mx);
        const float s  = e1 + e2;
        out[b*2+0] = e1 / s;
        out[b*2+1] = e2 / s;
    }
}

// ---------------------------------------------------------------- launch
extern "C" void kernel_launch(void* const* d_in, const int* in_sizes, int n_in,
                              void* d_out, int out_size, void* d_ws, size_t ws_size,
                              hipStream_t stream)
{
    const int*   ids  = (const int*)  d_in[0];
    const int*   ques = (const int*)  d_in[1];
    const int*   ans  = (const int*)  d_in[2];
    const float* E    = (const float*)d_in[3];
    const float* Uw   = (const float*)d_in[4];
    const float* Ubv  = (const float*)d_in[5];
    const float* Vw   = (const float*)d_in[6];
    const float* Vb   = (const float*)d_in[7];
    const float* Ww   = (const float*)d_in[8];
    const float* Wb   = (const float*)d_in[9];
    const float* sk   = (const float*)d_in[10];
    const float* Hw   = (const float*)d_in[11];
    const float* Hb   = (const float*)d_in[12];

    // workspace layout (floats): sT 1M | WsT 1M | vkey 2560 | qv/a1v/a2v 3*8192 | h 163840
    float* ws   = (float*)d_ws;
    float* sT   = ws;
    float* WsT  = sT  + 1048576;
    float* vkey = WsT + 1048576;
    float* qv   = vkey + 2560;
    float* a1v  = qv  + 8192;
    float* a2v  = a1v + 8192;
    float* h    = a2v + 8192;

    const int SCAN_LDS = (16384 + 64*129 + 128 + 128 + 16) * (int)sizeof(float); // 99648 B
    hipFuncSetAttribute((const void*)scan_kernel,
                        hipFuncAttributeMaxDynamicSharedMemorySize, SCAN_LDS);

    prep_kernel<<<1108, 128, 0, stream>>>(ids, ques, ans, E, Ww, Wb, Vw, Vb, sk,
                                          sT, WsT, vkey, qv, a1v, a2v);
    scan_kernel<<<20, 1024, SCAN_LDS, stream>>>(sT, WsT, vkey, Uw, Ubv, sk, h);
    final_kernel<<<64, 128, 0, stream>>>(h, qv, a1v, a2v, Hw, Hb, (float*)d_out);
}